// Round 7
// baseline (126.000 us; speedup 1.0000x reference)
//
#include <hip/hip_runtime.h>

typedef unsigned short u16;
typedef unsigned int u32;
typedef __attribute__((ext_vector_type(8))) short bf16x8;
typedef __attribute__((ext_vector_type(4))) float f32x4;

#define NJ 4094

__device__ __forceinline__ u16 f2bf(float f) {
  union { float f; unsigned u; } v;
  v.f = f;
  unsigned r = v.u + 0x7fffu + ((v.u >> 16) & 1u);
  return (u16)(r >> 16);
}

// pack hi16(a),hi16(b) -> u32 (a in low half), with +0x8000 round-half-up pre-added
__device__ __forceinline__ u32 pk_bf(float a, float b) {
  u32 ua = __float_as_uint(a) + 0x8000u;
  u32 ub = __float_as_uint(b) + 0x8000u;
  return __builtin_amdgcn_perm(ub, ua, 0x07060302u);  // bytes: ua.b2,ua.b3,ub.b2,ub.b3
}

// ---------------- dilated conv1d -> x2 (bf16, two layouts, j zero-padded to 4096) ----------------
// 256 blocks (j-tile = 32) so all 256 CUs are busy (R6 used 128 = half idle).
// WRITE_OUT: also out = x1 (only used in the atomic fallback path)
template <bool WRITE_OUT>
__global__ __launch_bounds__(256) void conv_kernel(
    const float* __restrict__ x, const float* __restrict__ w,
    const float* __restrict__ bias, u16* __restrict__ x2n, u16* __restrict__ x2T,
    float* __restrict__ out) {
  __shared__ float xs[64 * 36];       // [in_ch][36 window: j-1 .. j+34]
  __shared__ float wl[64 * 64 * 3];   // [in_ch][out_ch][tap]
  const int b = blockIdx.x >> 7, jt = blockIdx.x & 127;
  const int t = threadIdx.x;
  for (int idx = t; idx < 64 * 36; idx += 256) {
    int i = idx / 36, p = idx - i * 36;
    int jg = jt * 32 - 1 + p;          // window starts at j-1
    float v = 0.f;
    if (jg >= 0 && jg < 4096) v = x[(b * 64 + i) * 4096 + jg];
    xs[idx] = v;
  }
  for (int idx = t; idx < 64 * 64 * 3; idx += 256) {
    int tap = idx % 3, ci = idx / 3;
    int c = ci >> 6, i = ci & 63;      // source w[c][i][tap], coalesced read
    wl[(i * 64 + c) * 3 + tap] = w[idx];
  }
  __syncthreads();
  if (WRITE_OUT) {
    for (int idx = t; idx < 64 * 32; idx += 256) {
      int i = idx >> 5, k = idx & 31;
      out[(b * 64 + i) * 4096 + jt * 32 + k] = xs[i * 36 + k + 1];
    }
  }
  const int c = t & 63, jsub = t >> 6;   // each thread: 8 consecutive j
  float acc[8];
  float bv = bias[c];
#pragma unroll
  for (int k = 0; k < 8; k++) acc[k] = bv;
  for (int i = 0; i < 64; i++) {
    float w0 = wl[(i * 64 + c) * 3 + 0];
    float w1 = wl[(i * 64 + c) * 3 + 1];
    float w2 = wl[(i * 64 + c) * 3 + 2];
    const float* xr = &xs[i * 36 + jsub * 8];
#pragma unroll
    for (int k = 0; k < 8; k++)
      acc[k] += w0 * xr[k] + w1 * xr[k + 2] + w2 * xr[k + 4];
  }
#pragma unroll
  for (int k = 0; k < 8; k++) {
    int jg = jt * 32 + jsub * 8 + k;
    float v = (jg < NJ) ? acc[k] : 0.f;   // zero-pad j=4094,4095
    u16 hv = f2bf(v);
    x2n[(b * 64 + c) * 4096 + jg] = hv;   // [b][c][j]
    x2T[(b * 4096 + jg) * 64 + c] = hv;   // [b][j][c]
  }
}

// ---------------- fused kernel: R6 epilogue (no atomics) + R5 software pipeline ----------------
// Phase 1: wave owns a 16-j strip vs ALL 64 i: D = x2T(A, prefetched regs) . x1(B, regs,
//          b=1 negated) -> acc = S0-S1; sigmoid -> P rows to LDS (packed b64).
// Phase 2: D[m=c16][n=i16] = x2n(A, regs hoisted above barrier) . P(B, ds_read_b128).
// Pipeline: next tile's x2T frags load right after phase-1 MFMAs (hidden under
// sigmoid+phase2); current tile's x2n frags load before the barrier (hidden under
// barrier wait). Epilogue: plain coalesced stores to private partial region
// (R5 showed cross-XCD atomics poison L2: FETCH 9->54 MB, WRITE 32->101 MB).
template <bool ATOMIC>
__global__ __launch_bounds__(256, 4) void fused_kernel(
    const float* __restrict__ x, const u16* __restrict__ x2n_g,
    const u16* __restrict__ x2T_g, float* __restrict__ part_g,
    float* __restrict__ out) {
  __shared__ u16 P[2][2 * 64 * 72];   // [buf][b*64 + i_blk][j64 pad 72]
  const int t = threadIdx.x;
  const int wave = t >> 6, lane = t & 63;
  const int q = lane >> 4, ln = lane & 15;
  const int i0 = blockIdx.x * 64;
  const int jc = blockIdx.y;          // j-chunk: 4 tiles of 64

  // block-wide stage x1 -> P[1] as [b][i64][c pad72], b=1 sign-flipped (S0-S1 fold)
  u16* xs = P[1];
#pragma unroll
  for (int rep = 0; rep < 32; rep++) {
    int idx = rep * 256 + t;
    int il = idx & 63, c = (idx >> 6) & 63, b = idx >> 12;
    float v = x[(b * 64 + c) * 4096 + i0 + il];
    if (b) v = -v;
    xs[(b * 64 + il) * 72 + c] = f2bf(v);
  }
  __syncthreads();

  // x1 B-frags for all 4 i-subtiles, both batches: B[k=c][n=i]
  bf16x8 b1[2][4][2];
#pragma unroll
  for (int b = 0; b < 2; b++)
#pragma unroll
    for (int ist = 0; ist < 4; ist++)
#pragma unroll
      for (int kc = 0; kc < 2; kc++)
        b1[b][ist][kc] = *(const bf16x8*)&xs[(b * 64 + ist * 16 + ln) * 72 + kc * 32 + q * 8];

  f32x4 acc[2][4];   // phase-2 accumulators [c-strip][i-strip]
#pragma unroll
  for (int a = 0; a < 2; a++)
#pragma unroll
    for (int bq = 0; bq < 4; bq++) acc[a][bq] = (f32x4){0.f, 0.f, 0.f, 0.f};

  const int b2 = wave >> 1, cs2 = (wave & 1) * 2;  // phase-2 wave assignment
  const int jbase = jc * 4;

  // preload tile-0 x2T A-frags (wave's 16-j strip, both batches, K=64 in 2 chunks)
  bf16x8 afT[2][2];
  {
    const int j0 = jbase * 64;
#pragma unroll
    for (int b = 0; b < 2; b++)
#pragma unroll
      for (int kc = 0; kc < 2; kc++)
        afT[b][kc] = *(const bf16x8*)&x2T_g[(b * 4096 + j0 + wave * 16 + ln) * 64 + kc * 32 + q * 8];
  }

#pragma unroll
  for (int u = 0; u < 4; u++) {
    const int j0 = (jbase + u) * 64;
    u16* Ps = P[u & 1];               // jbase even -> jt&1 == u&1
    // ---- phase 1: wave's 16-j strip x all 64 i; d accumulated with b=1 negated
    f32x4 ps[4];
#pragma unroll
    for (int ist = 0; ist < 4; ist++) ps[ist] = (f32x4){0.f, 0.f, 0.f, 0.f};
#pragma unroll
    for (int b = 0; b < 2; b++)
#pragma unroll
      for (int kc = 0; kc < 2; kc++)
#pragma unroll
        for (int ist = 0; ist < 4; ist++)
          ps[ist] = __builtin_amdgcn_mfma_f32_16x16x32_bf16(afT[b][kc], b1[b][ist][kc], ps[ist], 0, 0, 0);
    // ---- prefetch next tile's x2T frags (latency hidden under sigmoid + phase 2)
    if (u < 3) {
      const int jn = j0 + 64;
#pragma unroll
      for (int b = 0; b < 2; b++)
#pragma unroll
        for (int kc = 0; kc < 2; kc++)
          afT[b][kc] = *(const bf16x8*)&x2T_g[(b * 4096 + jn + wave * 16 + ln) * 64 + kc * 32 + q * 8];
    }
    // ---- sigmoid: p0 = 1/(1+exp(-d)); lane rows j=wave*16+q*4+r, col i=ist*16+ln
#pragma unroll
    for (int ist = 0; ist < 4; ist++) {
      float p0[4], p1[4];
#pragma unroll
      for (int r = 0; r < 4; r++) {
        float e = __expf(-ps[ist][r]);
        p0[r] = __builtin_amdgcn_rcpf(1.f + e);
        p1[r] = 1.f - p0[r];
      }
      uint2 o0 = make_uint2(pk_bf(p0[0], p0[1]), pk_bf(p0[2], p0[3]));
      uint2 o1 = make_uint2(pk_bf(p1[0], p1[1]), pk_bf(p1[2], p1[3]));
      *(uint2*)&Ps[(0 + ist * 16 + ln) * 72 + wave * 16 + q * 4] = o0;    // b=0 rows
      *(uint2*)&Ps[(64 + ist * 16 + ln) * 72 + wave * 16 + q * 4] = o1;   // b=1 rows
    }
    // ---- hoist current tile's x2n A-frags above the barrier (independent of P)
    bf16x8 afN[2][2];
#pragma unroll
    for (int kc = 0; kc < 2; kc++)
#pragma unroll
      for (int cst = 0; cst < 2; cst++)
        afN[kc][cst] = *(const bf16x8*)&x2n_g[(b2 * 64 + (cs2 + cst) * 16 + ln) * 4096 + j0 + kc * 32 + q * 8];
    __syncthreads();   // only barrier per j-tile (dbuf covers WAR)
    // ---- phase 2: D[m=c16][n=i16], A = afN regs, B = P rows (ds_read_b128)
#pragma unroll
    for (int kc = 0; kc < 2; kc++) {
      bf16x8 pb[4];
#pragma unroll
      for (int ist = 0; ist < 4; ist++)
        pb[ist] = *(const bf16x8*)&Ps[(b2 * 64 + ist * 16 + ln) * 72 + kc * 32 + q * 8];
#pragma unroll
      for (int cst = 0; cst < 2; cst++)
#pragma unroll
        for (int ist = 0; ist < 4; ist++)
          acc[cst][ist] =
              __builtin_amdgcn_mfma_f32_16x16x32_bf16(afN[kc][cst], pb[ist], acc[cst][ist], 0, 0, 0);
    }
  }
  // ---- epilogue (coalesced: consecutive ln -> consecutive ii)
#pragma unroll
  for (int cst = 0; cst < 2; cst++)
#pragma unroll
    for (int ist = 0; ist < 4; ist++)
#pragma unroll
      for (int r = 0; r < 4; r++) {
        int c = (cs2 + cst) * 16 + q * 4 + r;
        int ii = i0 + ist * 16 + ln;
        if (ATOMIC) {
          unsafeAtomicAdd(&out[(b2 * 64 + c) * 4096 + ii], acc[cst][ist][r]);
        } else {
          part_g[(((jc * 2 + b2) * 64 + c) << 12) + ii] = acc[cst][ist][r];
        }
      }
}

// ---------------- out = x1 + sum_{jc} part[jc] (streaming, float4) ----------------
__global__ __launch_bounds__(256) void reduce_kernel(
    const float4* __restrict__ x, const float4* __restrict__ part,
    float4* __restrict__ out) {
  int i = blockIdx.x * 256 + threadIdx.x;    // over 2*64*4096/4 = 131072 float4
  float4 s = x[i];
#pragma unroll
  for (int jc = 0; jc < 16; jc++) {
    float4 p = part[jc * 131072 + i];
    s.x += p.x; s.y += p.y; s.z += p.z; s.w += p.w;
  }
  out[i] = s;
}

extern "C" void kernel_launch(void* const* d_in, const int* in_sizes, int n_in,
                              void* d_out, int out_size, void* d_ws, size_t ws_size,
                              hipStream_t stream) {
  const float* x = (const float*)d_in[0];
  const float* w = (const float*)d_in[1];
  const float* bias = (const float*)d_in[2];
  float* out = (float*)d_out;
  u16* x2n = (u16*)d_ws;                 // [2][64][4096] bf16 = 1 MB
  u16* x2T = x2n + 2 * 64 * 4096;        // [2][4096][64] bf16 = 1 MB
  float* part = (float*)(x2T + 2 * 64 * 4096);   // [16][2][64][4096] fp32 = 32 MB

  const size_t need = 2u * 64 * 4096 * 2 * 2 + 16u * 2 * 64 * 4096 * 4;
  dim3 grid(64, 16);
  if (ws_size >= need) {
    conv_kernel<false><<<256, 256, 0, stream>>>(x, w, bias, x2n, x2T, out);
    fused_kernel<false><<<grid, 256, 0, stream>>>(x, x2n, x2T, part, out);
    reduce_kernel<<<512, 256, 0, stream>>>((const float4*)x, (const float4*)part, (float4*)out);
  } else {
    // fallback: atomic accumulation into out (R4 path)
    conv_kernel<true><<<256, 256, 0, stream>>>(x, w, bias, x2n, x2T, out);
    fused_kernel<true><<<grid, 256, 0, stream>>>(x, x2n, x2T, nullptr, out);
  }
}

// Round 8
// 107.627 us; speedup vs baseline: 1.1707x; 1.1707x over previous
//
#include <hip/hip_runtime.h>

typedef unsigned short u16;
typedef unsigned int u32;
typedef __attribute__((ext_vector_type(8))) short bf16x8;
typedef __attribute__((ext_vector_type(4))) float f32x4;

#define NJ 4094

__device__ __forceinline__ u16 f2bf(float f) {
  union { float f; unsigned u; } v;
  v.f = f;
  unsigned r = v.u + 0x7fffu + ((v.u >> 16) & 1u);
  return (u16)(r >> 16);
}

// pack hi16(a),hi16(b) -> u32 (a in low half), with +0x8000 round-half-up pre-added
__device__ __forceinline__ u32 pk_bf(float a, float b) {
  u32 ua = __float_as_uint(a) + 0x8000u;
  u32 ub = __float_as_uint(b) + 0x8000u;
  return __builtin_amdgcn_perm(ub, ua, 0x07060302u);  // bytes: ua.b2,ua.b3,ub.b2,ub.b3
}

// ---------------- dilated conv1d -> x2 (bf16, two layouts, j zero-padded to 4096) ----------------
// 256 blocks (j-tile = 32) so all 256 CUs are busy.
// WRITE_OUT: also out = x1 (only used in the atomic fallback path)
template <bool WRITE_OUT>
__global__ __launch_bounds__(256) void conv_kernel(
    const float* __restrict__ x, const float* __restrict__ w,
    const float* __restrict__ bias, u16* __restrict__ x2n, u16* __restrict__ x2T,
    float* __restrict__ out) {
  __shared__ float xs[64 * 36];       // [in_ch][36 window: j-1 .. j+34]
  __shared__ float wl[64 * 64 * 3];   // [in_ch][out_ch][tap]
  const int b = blockIdx.x >> 7, jt = blockIdx.x & 127;
  const int t = threadIdx.x;
  for (int idx = t; idx < 64 * 36; idx += 256) {
    int i = idx / 36, p = idx - i * 36;
    int jg = jt * 32 - 1 + p;          // window starts at j-1
    float v = 0.f;
    if (jg >= 0 && jg < 4096) v = x[(b * 64 + i) * 4096 + jg];
    xs[idx] = v;
  }
  for (int idx = t; idx < 64 * 64 * 3; idx += 256) {
    int tap = idx % 3, ci = idx / 3;
    int c = ci >> 6, i = ci & 63;      // source w[c][i][tap], coalesced read
    wl[(i * 64 + c) * 3 + tap] = w[idx];
  }
  __syncthreads();
  if (WRITE_OUT) {
    for (int idx = t; idx < 64 * 32; idx += 256) {
      int i = idx >> 5, k = idx & 31;
      out[(b * 64 + i) * 4096 + jt * 32 + k] = xs[i * 36 + k + 1];
    }
  }
  const int c = t & 63, jsub = t >> 6;   // each thread: 8 consecutive j
  float acc[8];
  float bv = bias[c];
#pragma unroll
  for (int k = 0; k < 8; k++) acc[k] = bv;
  for (int i = 0; i < 64; i++) {
    float w0 = wl[(i * 64 + c) * 3 + 0];
    float w1 = wl[(i * 64 + c) * 3 + 1];
    float w2 = wl[(i * 64 + c) * 3 + 2];
    const float* xr = &xs[i * 36 + jsub * 8];
#pragma unroll
    for (int k = 0; k < 8; k++)
      acc[k] += w0 * xr[k] + w1 * xr[k + 2] + w2 * xr[k + 4];
  }
#pragma unroll
  for (int k = 0; k < 8; k++) {
    int jg = jt * 32 + jsub * 8 + k;
    float v = (jg < NJ) ? acc[k] : 0.f;   // zero-pad j=4094,4095
    u16 hv = f2bf(v);
    x2n[(b * 64 + c) * 4096 + jg] = hv;   // [b][c][j]
    x2T[(b * 4096 + jg) * 64 + c] = hv;   // [b][j][c]
  }
}

// ---------------- fused kernel: EXACT R6 structure (rolled loop, loads in place).
// R5/R7 showed the "software pipeline" (full unroll + prefetch + hoist) trips a
// register cliff -> scratch spills: FETCH 9->55 MB, WRITE 32->101 MB, +20 us. Do NOT re-add.
// Phase 1: wave owns a 16-j strip vs ALL 64 i: D = x2T(A, 4 loads) . x1(B, regs, b=1 negated)
//          -> acc = S0-S1; sigmoid -> P rows to LDS (packed b64).
// Phase 2: D[m=c16][n=i16] = x2n(A, global) . P(B, ds_read_b128).
// Epilogue: plain coalesced stores to private partial region.
template <bool ATOMIC>
__global__ __launch_bounds__(256, 4) void fused_kernel(
    const float* __restrict__ x, const u16* __restrict__ x2n_g,
    const u16* __restrict__ x2T_g, float* __restrict__ part_g,
    float* __restrict__ out) {
  __shared__ u16 P[2][2 * 64 * 72];   // [buf][b*64 + i_blk][j64 pad 72]
  const int t = threadIdx.x;
  const int wave = t >> 6, lane = t & 63;
  const int q = lane >> 4, ln = lane & 15;
  const int i0 = blockIdx.x * 64;
  const int jc = blockIdx.y;          // j-chunk: 4 tiles of 64

  // block-wide stage x1 -> P[1] as [b][i64][c pad72], b=1 sign-flipped (S0-S1 fold)
  u16* xs = P[1];
#pragma unroll
  for (int rep = 0; rep < 32; rep++) {
    int idx = rep * 256 + t;
    int il = idx & 63, c = (idx >> 6) & 63, b = idx >> 12;
    float v = x[(b * 64 + c) * 4096 + i0 + il];
    if (b) v = -v;
    xs[(b * 64 + il) * 72 + c] = f2bf(v);
  }
  __syncthreads();

  // x1 B-frags for all 4 i-subtiles, both batches: B[k=c][n=i]
  bf16x8 b1[2][4][2];
#pragma unroll
  for (int b = 0; b < 2; b++)
#pragma unroll
    for (int ist = 0; ist < 4; ist++)
#pragma unroll
      for (int kc = 0; kc < 2; kc++)
        b1[b][ist][kc] = *(const bf16x8*)&xs[(b * 64 + ist * 16 + ln) * 72 + kc * 32 + q * 8];

  f32x4 acc[2][4];   // phase-2 accumulators [c-strip][i-strip]
#pragma unroll
  for (int a = 0; a < 2; a++)
#pragma unroll
    for (int bq = 0; bq < 4; bq++) acc[a][bq] = (f32x4){0.f, 0.f, 0.f, 0.f};

  const int b2 = wave >> 1, cs2 = (wave & 1) * 2;  // phase-2 wave assignment

  for (int jt = jc * 4; jt < jc * 4 + 4; jt++) {
    const int j0 = jt * 64;
    u16* Ps = P[jt & 1];
    // ---- phase 1: wave's 16-j strip x all 64 i; d accumulated with b=1 negated
    f32x4 ps[4];
#pragma unroll
    for (int ist = 0; ist < 4; ist++) ps[ist] = (f32x4){0.f, 0.f, 0.f, 0.f};
#pragma unroll
    for (int b = 0; b < 2; b++)
#pragma unroll
      for (int kc = 0; kc < 2; kc++) {
        bf16x8 af = *(const bf16x8*)&x2T_g[(b * 4096 + j0 + wave * 16 + ln) * 64 + kc * 32 + q * 8];
#pragma unroll
        for (int ist = 0; ist < 4; ist++)
          ps[ist] = __builtin_amdgcn_mfma_f32_16x16x32_bf16(af, b1[b][ist][kc], ps[ist], 0, 0, 0);
      }
    // ---- sigmoid: p0 = 1/(1+exp(-d)); lane rows j=wave*16+q*4+r, col i=ist*16+ln
#pragma unroll
    for (int ist = 0; ist < 4; ist++) {
      float p0[4], p1[4];
#pragma unroll
      for (int r = 0; r < 4; r++) {
        float e = __expf(-ps[ist][r]);
        p0[r] = __builtin_amdgcn_rcpf(1.f + e);
        p1[r] = 1.f - p0[r];
      }
      uint2 o0 = make_uint2(pk_bf(p0[0], p0[1]), pk_bf(p0[2], p0[3]));
      uint2 o1 = make_uint2(pk_bf(p1[0], p1[1]), pk_bf(p1[2], p1[3]));
      *(uint2*)&Ps[(0 + ist * 16 + ln) * 72 + wave * 16 + q * 4] = o0;    // b=0 rows
      *(uint2*)&Ps[(64 + ist * 16 + ln) * 72 + wave * 16 + q * 4] = o1;   // b=1 rows
    }
    __syncthreads();   // only barrier per j-tile (dbuf covers WAR)
    // ---- phase 2: D[m=c16][n=i16], A = x2n rows (16B global), B = P rows (ds_read_b128)
#pragma unroll
    for (int kc = 0; kc < 2; kc++) {
      bf16x8 af2[2], pb[4];
#pragma unroll
      for (int cst = 0; cst < 2; cst++)
        af2[cst] = *(const bf16x8*)&x2n_g[(b2 * 64 + (cs2 + cst) * 16 + ln) * 4096 + j0 + kc * 32 + q * 8];
#pragma unroll
      for (int ist = 0; ist < 4; ist++)
        pb[ist] = *(const bf16x8*)&Ps[(b2 * 64 + ist * 16 + ln) * 72 + kc * 32 + q * 8];
#pragma unroll
      for (int cst = 0; cst < 2; cst++)
#pragma unroll
        for (int ist = 0; ist < 4; ist++)
          acc[cst][ist] =
              __builtin_amdgcn_mfma_f32_16x16x32_bf16(af2[cst], pb[ist], acc[cst][ist], 0, 0, 0);
    }
  }
  // ---- epilogue (coalesced: consecutive ln -> consecutive ii)
#pragma unroll
  for (int cst = 0; cst < 2; cst++)
#pragma unroll
    for (int ist = 0; ist < 4; ist++)
#pragma unroll
      for (int r = 0; r < 4; r++) {
        int c = (cs2 + cst) * 16 + q * 4 + r;
        int ii = i0 + ist * 16 + ln;
        if (ATOMIC) {
          unsafeAtomicAdd(&out[(b2 * 64 + c) * 4096 + ii], acc[cst][ist][r]);
        } else {
          part_g[(((jc * 2 + b2) * 64 + c) << 12) + ii] = acc[cst][ist][r];
        }
      }
}

// ---------------- out = x1 + sum_{jc} part[jc] (streaming, float4) ----------------
__global__ __launch_bounds__(256) void reduce_kernel(
    const float4* __restrict__ x, const float4* __restrict__ part,
    float4* __restrict__ out) {
  int i = blockIdx.x * 256 + threadIdx.x;    // over 2*64*4096/4 = 131072 float4
  float4 s = x[i];
#pragma unroll
  for (int jc = 0; jc < 16; jc++) {
    float4 p = part[jc * 131072 + i];
    s.x += p.x; s.y += p.y; s.z += p.z; s.w += p.w;
  }
  out[i] = s;
}

extern "C" void kernel_launch(void* const* d_in, const int* in_sizes, int n_in,
                              void* d_out, int out_size, void* d_ws, size_t ws_size,
                              hipStream_t stream) {
  const float* x = (const float*)d_in[0];
  const float* w = (const float*)d_in[1];
  const float* bias = (const float*)d_in[2];
  float* out = (float*)d_out;
  u16* x2n = (u16*)d_ws;                 // [2][64][4096] bf16 = 1 MB
  u16* x2T = x2n + 2 * 64 * 4096;        // [2][4096][64] bf16 = 1 MB
  float* part = (float*)(x2T + 2 * 64 * 4096);   // [16][2][64][4096] fp32 = 32 MB

  const size_t need = 2u * 64 * 4096 * 2 * 2 + 16u * 2 * 64 * 4096 * 4;
  dim3 grid(64, 16);
  if (ws_size >= need) {
    conv_kernel<false><<<256, 256, 0, stream>>>(x, w, bias, x2n, x2T, out);
    fused_kernel<false><<<grid, 256, 0, stream>>>(x, x2n, x2T, part, out);
    reduce_kernel<<<512, 256, 0, stream>>>((const float4*)x, (const float4*)part, (float4*)out);
  } else {
    // fallback: atomic accumulation into out (R4 path)
    conv_kernel<true><<<256, 256, 0, stream>>>(x, w, bias, x2n, x2T, out);
    fused_kernel<true><<<grid, 256, 0, stream>>>(x, x2n, x2T, nullptr, out);
  }
}